// Round 13
// baseline (469.865 us; speedup 1.0000x reference)
//
#include <hip/hip_runtime.h>
#include <hip/hip_bf16.h>

#define B_   8
#define S_   1024
#define HID_ 1024
#define H_   16
#define D_   64

typedef __hip_bfloat16 bf16;
typedef __attribute__((ext_vector_type(8))) short s16x8;   // MFMA A/B frag (8 bf16)
typedef __attribute__((ext_vector_type(4))) float f32x4;   // MFMA C/D frag

// Fragment-order workspace layouts (indices in bf16 elements):
//  Qf/Kf: per bh (128 KiB): 64 row-tiles of 16 rows; per tile 1024 elems =
//         [half(2)][lane(64)][8]; lane (quad,c) holds row c, features
//         half*32+quad*8..+8  (exactly the attn A/B frag).
//  Vf:    per bh: 16 key-tiles; per tile 4096 = [et(4)][p(2)][lane(64)][8];
//         lane slot = V[key p*32+quad*4+j][feat et*16+c] (j=0..3), key+16
//         for j=4..7 — the paired-chunk PV B-frag.
//  Wf:    per (m,h): 4096 = [et(4)][half(2)][lane(64)][8].
#define QK_BH 65536
#define V_BH  65536

// packed f32x2 -> bf16x2 (v_cvt_pk_bf16_f32, RNE)
__device__ __forceinline__ unsigned pk2(float a, float b) {
    __hip_bfloat162 h = __float22bfloat162_rn(make_float2(a, b));
    return *(unsigned*)&h;
}
// load 8 consecutive f32 (32B, aligned) -> bf16 half-fragment (packed cvt)
__device__ __forceinline__ s16x8 cvt8(const float* p) {
    const float4* q = (const float4*)p;
    float4 u = q[0], v = q[1];
    union { s16x8 v; unsigned w[4]; } r;
    r.w[0] = pk2(u.x, u.y);
    r.w[1] = pk2(u.z, u.w);
    r.w[2] = pk2(v.x, v.y);
    r.w[3] = pk2(v.z, v.w);
    return r.v;
}
__device__ __forceinline__ s16x8 load8bf(const bf16* p) {
    return *(const s16x8*)p;   // 16B load; callers guarantee alignment
}

// ---------------------------------------------------------------------------
// Kernel 0: one-shot W f32 -> bf16 in FRAGMENT ORDER.
// ---------------------------------------------------------------------------
__global__ __launch_bounds__(256) void cvt_w(
    const float* __restrict__ Wq, const float* __restrict__ Wk,
    const float* __restrict__ Wv, bf16* __restrict__ Wf)
{
    const float* srcs[3] = {Wq, Wk, Wv};
    const float* src = srcs[blockIdx.y];
    bf16* dst = Wf + (size_t)blockIdx.y * (H_ * D_ * D_);
    const int i = blockIdx.x * 256 + threadIdx.x;   // 0..8191
    const int h = i >> 9;            // 512 threads per head
    const int r = i & 511;
    const int et = r >> 7, half = (r >> 6) & 1, lane = r & 63;
    const int quad = lane >> 4, c = lane & 15;
    const float* s = src + h * 4096 + (et * 16 + c) * 64 + half * 32 + quad * 8;
    bf16* d = dst + h * 4096 + et * 1024 + half * 512 + lane * 8;
    *(s16x8*)d = cvt8(s);
}

// ---------------------------------------------------------------------------
// Kernel 1: QKV projection, FRAGMENT-ORDER outputs, 64-row blocks.
// grid 2048 (bh = id&127, sc = id>>7), block 256; wave owns 16 rows.
// ---------------------------------------------------------------------------
__global__ __launch_bounds__(256) void qkv_proj(
    const float* __restrict__ x, const bf16* __restrict__ Wf,
    const float* __restrict__ bq, const float* __restrict__ bk,
    const float* __restrict__ bv,
    bf16* __restrict__ Qf, bf16* __restrict__ Kf, bf16* __restrict__ Vf)
{
    __shared__ __align__(16) bf16 xs[64][72];   // 9 KiB, stride-72 padding

    const int id = blockIdx.x;
    const int bh_i = id & 127, sc = id >> 7;    // sc: 64-row chunk 0..15
    const int b = bh_i >> 4, h = bh_i & 15;
    const int t = threadIdx.x;
    const int wave = t >> 6, lane = t & 63;
    const int quad = lane >> 4, c = lane & 15;
    const size_t bh = (size_t)bh_i;

    // ---- stage x[rows sc*64..+64)[h*64..+64) -> bf16 LDS, coalesced ----
    {
        const float* xg = x + ((size_t)b * S_ + sc * 64) * HID_ + h * D_;
#pragma unroll
        for (int i = 0; i < 4; ++i) {
            const int j = i * 256 + t;          // 1024 float4 segments
            const int row = j >> 4, seg = j & 15;
            float4 v = *(const float4*)(xg + (size_t)row * HID_ + seg * 4);
            uint2 pk;
            pk.x = pk2(v.x, v.y);
            pk.y = pk2(v.z, v.w);
            *(uint2*)&xs[row][seg * 4] = pk;
        }
    }
    __syncthreads();

    // X frag for this wave's row-tile (rows wave*16 + c)
    s16x8 xa0 = *(const s16x8*)&xs[wave * 16 + c][quad * 8];
    s16x8 xa1 = *(const s16x8*)&xs[wave * 16 + c][32 + quad * 8];

    const float* bs[3] = {bq, bk, bv};

#pragma unroll
    for (int m = 0; m < 3; ++m) {
        const bf16*  Wm   = Wf + ((size_t)m * H_ + h) * 4096;
        const float* bias = bs[m] + h * D_;
#pragma unroll
        for (int et = 0; et < 4; ++et) {
            s16x8 wf0 = load8bf(Wm + et * 1024 + lane * 8);         // half 0
            s16x8 wf1 = load8bf(Wm + et * 1024 + 512 + lane * 8);   // half 1
            if (m < 2) {
                // D[e][s] = W·X^T : lane holds feats f = et*16+quad*4+r of
                // row (sc*4+wave)*16 + c.
                const int hp = et >> 1;
                const int qp = (2 * et + (quad >> 1)) & 3;
                const float4 bb = *(const float4*)&bias[et * 16 + quad * 4];
                f32x4 acc = {0.f, 0.f, 0.f, 0.f};
                acc = __builtin_amdgcn_mfma_f32_16x16x32_bf16(wf0, xa0, acc, 0, 0, 0);
                acc = __builtin_amdgcn_mfma_f32_16x16x32_bf16(wf1, xa1, acc, 0, 0, 0);
                const int ts = sc * 4 + wave;   // row-tile index
                bf16* dst = (m == 0 ? Qf : Kf) + bh * QK_BH + ts * 1024 +
                            hp * 512 + (qp * 16 + c) * 8 + (quad & 1) * 4;
                uint2 pk;
                pk.x = pk2(acc[0] + bb.x, acc[1] + bb.y);
                pk.y = pk2(acc[2] + bb.z, acc[3] + bb.w);
                *(uint2*)dst = pk;
            } else {
                // D[s][e] = X·W^T : lane holds keys wave*16+quad*4+r of
                // feature et*16+c. Key-tile = sc; p = wave>>1, hi = wave&1.
                const float bbv = bias[et * 16 + c];
                f32x4 acc = {0.f, 0.f, 0.f, 0.f};
                acc = __builtin_amdgcn_mfma_f32_16x16x32_bf16(xa0, wf0, acc, 0, 0, 0);
                acc = __builtin_amdgcn_mfma_f32_16x16x32_bf16(xa1, wf1, acc, 0, 0, 0);
                bf16* dst = Vf + bh * V_BH + sc * 4096 + et * 1024 +
                            (wave >> 1) * 512 + (quad * 16 + c) * 8 + (wave & 1) * 4;
                uint2 pk;
                pk.x = pk2(acc[0] + bbv, acc[1] + bbv);
                pk.y = pk2(acc[2] + bbv, acc[3] + bbv);
                *(uint2*)dst = pk;
            }
        }
    }
}

// ---------------------------------------------------------------------------
// Kernel 2: MFMA flash attention, 64 q-rows per WAVE-PAIR with split-K:
// block = 512 threads = 8 waves = 4 pairs; wave hk=w&1 of pair p processes
// keys hk*512..+512 (8 iters). Fixed-shift softmax partials combine exactly
// (no max coupling): O = O0+O1, L = L0+L1 via LDS (f32, 2 phases).
// Register-resident P (swap trick), fragment-order coalesced loads.
// grid 512 (bh = id&127, qq = id>>7): 2 blocks/CU -> 4 waves/SIMD at
// VGPR<=128 (R12 measured 120 for the same loop body).
// ---------------------------------------------------------------------------
__global__ __launch_bounds__(512, 4) void attn(
    const bf16* __restrict__ Qf, const bf16* __restrict__ Kf,
    const bf16* __restrict__ Vf, float* __restrict__ out)
{
    __shared__ __align__(16) float cmb[4][64][33];  // 33.8 KB (stride 33: conflict-free)
    __shared__ float lbuf[4][64][4];                // 4 KB
    __shared__ __align__(16) float os[4][16][68];   // 17.4 KB, per-pair staging

    const int id = blockIdx.x;
    const int bh_i = id & 127, qq = id >> 7;        // qq 0..3 (256 rows each)
    const int b = bh_i >> 4, h = bh_i & 15;
    const int wave = threadIdx.x >> 6, lane = threadIdx.x & 63;
    const int pair = wave >> 1, hk = wave & 1;
    const int quad = lane >> 4, c = lane & 15;
    const int ts0 = qq * 16 + pair * 4;             // first of 4 row-tiles
    const size_t bh = (size_t)bh_i;

    // Q fragments for 4 row-tiles (B-operand of swapped QK); both hk waves
    // of a pair load the same Q.
    s16x8 aq[4][2];
#pragma unroll
    for (int mt = 0; mt < 4; ++mt) {
        const bf16* Qb = Qf + bh * QK_BH + (ts0 + mt) * 1024 + lane * 8;
        aq[mt][0] = load8bf(Qb);
        aq[mt][1] = load8bf(Qb + 512);
    }

    f32x4 o[4][4];
#pragma unroll
    for (int mt = 0; mt < 4; ++mt)
#pragma unroll
        for (int et = 0; et < 4; ++et) o[mt][et] = {0.f, 0.f, 0.f, 0.f};
    float l[4] = {0.f, 0.f, 0.f, 0.f};   // per-lane partial denoms

    const float CEXP = 0.18033688011112042f;           // (1/sqrt(64))*log2(e)
    const float NM0  = -16.0f * 0.18033688011112042f;  // fixed shift m0=16

    const bf16* Kb = Kf + bh * QK_BH + lane * 8;
    const bf16* Vb = Vf + bh * V_BH  + lane * 8;

#pragma unroll 1
    for (int ki = 0; ki < 8; ++ki) {
        const int kt = hk * 8 + ki;   // this wave's key-half
        // ---- coalesced tile loads (16 independent 16B loads) ----
        s16x8 ka[4], kb2[4];
#pragma unroll
        for (int ct = 0; ct < 4; ++ct) {
            ka[ct]  = load8bf(Kb + (kt * 4 + ct) * 1024);
            kb2[ct] = load8bf(Kb + (kt * 4 + ct) * 1024 + 512);
        }
        s16x8 vf4[4][2];
#pragma unroll
        for (int et = 0; et < 4; ++et)
#pragma unroll
            for (int p = 0; p < 2; ++p)
                vf4[et][p] = load8bf(Vb + kt * 4096 + et * 1024 + p * 512);

        // ---- per row-tile: QK^T -> softmax -> PV (P stays in registers) --
#pragma unroll
        for (int mt = 0; mt < 4; ++mt) {
            f32x4 s[4];
#pragma unroll
            for (int ct = 0; ct < 4; ++ct) {
                f32x4 acc = {0.f, 0.f, 0.f, 0.f};
                acc = __builtin_amdgcn_mfma_f32_16x16x32_bf16(ka[ct],  aq[mt][0], acc, 0, 0, 0);
                acc = __builtin_amdgcn_mfma_f32_16x16x32_bf16(kb2[ct], aq[mt][1], acc, 0, 0, 0);
                s[ct] = acc;
            }
            s16x8 pz[2];
#pragma unroll
            for (int p = 0; p < 2; ++p) {
                union { s16x8 v; unsigned w[4]; } z;
                float e0 = __builtin_amdgcn_exp2f(fmaf(s[2 * p][0],     CEXP, NM0));
                float e1 = __builtin_amdgcn_exp2f(fmaf(s[2 * p][1],     CEXP, NM0));
                float e2 = __builtin_amdgcn_exp2f(fmaf(s[2 * p][2],     CEXP, NM0));
                float e3 = __builtin_amdgcn_exp2f(fmaf(s[2 * p][3],     CEXP, NM0));
                float e4 = __builtin_amdgcn_exp2f(fmaf(s[2 * p + 1][0], CEXP, NM0));
                float e5 = __builtin_amdgcn_exp2f(fmaf(s[2 * p + 1][1], CEXP, NM0));
                float e6 = __builtin_amdgcn_exp2f(fmaf(s[2 * p + 1][2], CEXP, NM0));
                float e7 = __builtin_amdgcn_exp2f(fmaf(s[2 * p + 1][3], CEXP, NM0));
                l[mt] += (e0 + e1) + (e2 + e3) + (e4 + e5) + (e6 + e7);
                z.w[0] = pk2(e0, e1);
                z.w[1] = pk2(e2, e3);
                z.w[2] = pk2(e4, e5);
                z.w[3] = pk2(e6, e7);
                pz[p] = z.v;
            }
#pragma unroll
            for (int et = 0; et < 4; ++et) {
                o[mt][et] = __builtin_amdgcn_mfma_f32_16x16x32_bf16(pz[0], vf4[et][0], o[mt][et], 0, 0, 0);
                o[mt][et] = __builtin_amdgcn_mfma_f32_16x16x32_bf16(pz[1], vf4[et][1], o[mt][et], 0, 0, 0);
            }
        }
    }

    // ---- split-K combine (f32, two phases) + epilogue by hk=0 waves ----
    // phase A: partner writes o[0..1] + l
    if (hk == 1) {
#pragma unroll
        for (int mt = 0; mt < 2; ++mt)
#pragma unroll
            for (int et = 0; et < 4; ++et)
#pragma unroll
                for (int r = 0; r < 4; ++r)
                    cmb[pair][lane][mt * 16 + et * 4 + r] = o[mt][et][r];
#pragma unroll
        for (int mt = 0; mt < 4; ++mt) lbuf[pair][lane][mt] = l[mt];
    }
    __syncthreads();
    float Lfull[4];
    if (hk == 0) {
#pragma unroll
        for (int mt = 0; mt < 4; ++mt) Lfull[mt] = l[mt] + lbuf[pair][lane][mt];
#pragma unroll
        for (int mt = 0; mt < 2; ++mt)
#pragma unroll
            for (int et = 0; et < 4; ++et)
#pragma unroll
                for (int r = 0; r < 4; ++r)
                    o[mt][et][r] += cmb[pair][lane][mt * 16 + et * 4 + r];
    }
    __syncthreads();
    // phase B: partner writes o[2..3]
    if (hk == 1) {
#pragma unroll
        for (int mt = 2; mt < 4; ++mt)
#pragma unroll
            for (int et = 0; et < 4; ++et)
#pragma unroll
                for (int r = 0; r < 4; ++r)
                    cmb[pair][lane][(mt - 2) * 16 + et * 4 + r] = o[mt][et][r];
    }
    __syncthreads();
    if (hk == 0) {
#pragma unroll
        for (int mt = 2; mt < 4; ++mt)
#pragma unroll
            for (int et = 0; et < 4; ++et)
#pragma unroll
                for (int r = 0; r < 4; ++r)
                    o[mt][et][r] += cmb[pair][lane][(mt - 2) * 16 + et * 4 + r];

        // epilogue: quad-sum denom, normalize, LDS transpose, float4 stores
#pragma unroll
        for (int mt = 0; mt < 4; ++mt) {
            float L = Lfull[mt];
            L += __shfl_xor(L, 16, 64);
            L += __shfl_xor(L, 32, 64);
            const float Linv = 1.0f / L;
            float inv[4];
#pragma unroll
            for (int r = 0; r < 4; ++r)
                inv[r] = __shfl(Linv, quad * 4 + r, 64);
#pragma unroll
            for (int et = 0; et < 4; ++et)
#pragma unroll
                for (int r = 0; r < 4; ++r)
                    os[pair][quad * 4 + r][et * 16 + c] = o[mt][et][r] * inv[r];
            float* orow = out + ((size_t)b * S_ + (ts0 + mt) * 16 + c) * HID_ + h * D_;
#pragma unroll
            for (int j = 0; j < 4; ++j) {
                float4 v = *(const float4*)&os[pair][c][(quad + j * 4) * 4];
                *(float4*)(orow + (quad + j * 4) * 4) = v;
            }
        }
    }
}

// ---------------------------------------------------------------------------
extern "C" void kernel_launch(void* const* d_in, const int* in_sizes, int n_in,
                              void* d_out, int out_size, void* d_ws, size_t ws_size,
                              hipStream_t stream) {
    (void)in_sizes; (void)n_in; (void)out_size; (void)ws_size;
    const float* x  = (const float*)d_in[0];
    const float* Wq = (const float*)d_in[1];
    const float* bq = (const float*)d_in[2];
    const float* Wk = (const float*)d_in[3];
    const float* bk = (const float*)d_in[4];
    const float* Wv = (const float*)d_in[5];
    const float* bv = (const float*)d_in[6];
    float* outp = (float*)d_out;   // reference output dtype is float32

    bf16* Qfw = (bf16*)d_ws;                       // 128 bh * 64K elems
    bf16* Kfw = Qfw + (size_t)128 * QK_BH;
    bf16* Vfw = Kfw + (size_t)128 * QK_BH;
    bf16* Wfw = Vfw + (size_t)128 * V_BH;          // + 384 KiB fragment-order W

    cvt_w<<<dim3(32, 3), 256, 0, stream>>>(Wq, Wk, Wv, Wfw);
    qkv_proj<<<dim3(2048), 256, 0, stream>>>(x, Wfw, bq, bk, bv, Qfw, Kfw, Vfw);
    attn<<<dim3(512), 512, 0, stream>>>(Qfw, Kfw, Vfw, outp);
}